// Round 3
// baseline (96.038 us; speedup 1.0000x reference)
//
#include <hip/hip_runtime.h>
#include <math.h>

// QuadConvLayer: out[b,o,m] = sum_{c,k} MLP_{o,c}(x(m,k))*bump(x)*w2d(k) * f[b,c,k]
// Compact support ||x|| < 1/6 -> per output loc, active quad nodes form a
// <=6 x <=6 window (24-pt GL node spacing vs radius 1/6; verified offline).
//
// Grid (slot=8, m=144): block handles the slot-th active ik row of m.
// - Row list computed inline from QN (uniform scalar scan, no setup kernel).
// - Stage only an 8-float aligned jk window (16 KB LDS) instead of 48 KB row.
// - kv evaluated branch-free at 6 consecutive jk; bump==0 masks inactive
//   positions exactly (same predicate as the reference's `where`).
// - shuffle c-reduce, atomicAdd into OUT (<=6 colliding blocks per m);
//   OUT zeroed by hipMemsetAsync in-graph.

#define NQ 24
#define M_TOT 144
#define NB 32
#define SLOTS 8
#define R2MAX (1.0f / 36.0f)

__device__ __forceinline__ float sin_poly(float x) {
    // |x| <= ~0.8 inside bump support; fdlibm coeffs, err < 1e-9
    float z = x * x;
    float r = fmaf(z, 2.7557313707070068e-06f, -1.9841269659586510e-04f);
    r = fmaf(z, r, 8.3333333332248946e-03f);
    r = fmaf(z, r, -1.6666666666666632e-01f);
    return fmaf(x * z, r, x);
}

__global__ __launch_bounds__(256, 2)
void quadconv_kernel(const float* __restrict__ F,    // (32,16,576)
                     const float* __restrict__ OL,   // (144,2)
                     const float* __restrict__ QN,   // (24,)
                     const float* __restrict__ QW,   // (24,)
                     const float* __restrict__ W1,   // (16,16,2,8)
                     const float* __restrict__ W2,   // (16,16,8,8)
                     const float* __restrict__ W3,   // (16,16,8,1)
                     float* __restrict__ OUT) {      // (32,16,144)
    const int slot = blockIdx.x;
    const int m    = blockIdx.y;
    const int t    = threadIdx.x;
    const int c    = t & 15;
    const int o    = t >> 4;

    const float ox = OL[2 * m];
    const float oy = OL[2 * m + 1];

    // ---- slot-th active ik row (uniform scalar scan) ----
    int ik = -1, cnt = 0;
    for (int i = 0; i < NQ; ++i) {
        float d = oy - QN[i];
        if (d * d < R2MAX) { if (cnt == slot) ik = i; ++cnt; }
    }
    if (ik < 0) return;                       // uniform exit, no LDS touched
    const float x1 = oy - QN[ik];
    const float x1sq = x1 * x1;

    // ---- active jk window (uniform) ----
    const float lim = R2MAX - x1sq;
    int jk0 = NQ, jk1 = -1;
    for (int j = 0; j < NQ; ++j) {
        float d = ox - QN[j];
        if (d * d < lim) { if (jk1 < 0) jk0 = j; jk1 = j; }
    }
    if (jk1 < 0) return;                      // uniform
    jk0 = min(jk0, 18);                       // keep [jk0, jk0+5] in-row
    const int w0   = min(jk0 & ~1, 16);       // 8-float window, float2-aligned
    const int joff = jk0 - w0;                // 0..2 (uniform)

    __shared__ float f_s[8 * 512];            // f_s[jw*512 + b*16 + c], 16 KB

    // ---- issue staging loads: 8-k window for pairs t and t+256 ----
    const int kbase = ik * NQ + w0;
    float2 q[8];
    {
        const float* base = F + (t >> 4) * 9216 + (t & 15) * 576 + kbase;
        const float2* s0 = (const float2*)base;
        const float2* s1 = (const float2*)(base + 16 * 9216);
        #pragma unroll
        for (int i = 0; i < 4; ++i) { q[i] = s0[i]; q[i + 4] = s1[i]; }
    }

    // ---- per-thread MLP weights (registers) ----
    float w1r[16], w2r[64], w3r[8];
    {
        const float4* p1 = (const float4*)(W1 + t * 16);
        #pragma unroll
        for (int i = 0; i < 4; ++i) ((float4*)w1r)[i] = p1[i];
        const float4* p2 = (const float4*)(W2 + t * 64);
        #pragma unroll
        for (int i = 0; i < 16; ++i) ((float4*)w2r)[i] = p2[i];
        const float4* p3 = (const float4*)(W3 + t * 8);
        #pragma unroll
        for (int i = 0; i < 2; ++i) ((float4*)w3r)[i] = p3[i];
    }

    // ---- kv for 6 consecutive jk (bump==0 masks inactive positions) ----
    const float qwik = QW[ik];
    float kvr[6];
    #pragma unroll
    for (int j = 0; j < 6; ++j) {
        const int jk = jk0 + j;
        const float x0 = ox - QN[jk];
        const float r2 = fmaf(x0, x0, x1sq);
        const float da = 1296.0f * r2 * r2;
        float kv = 0.0f;
        if (da < 1.0f) {                      // uniform branch
            const float kscale =
                2.718281828459045f * __expf(-1.0f / (1.0f - da)) * qwik * QW[jk];
            float h1[8];
            #pragma unroll
            for (int h = 0; h < 8; ++h)
                h1[h] = sin_poly(fmaf(x0, w1r[h], x1 * w1r[8 + h]));
            float wsum = 0.0f;
            #pragma unroll
            for (int g = 0; g < 8; ++g) {
                float z = h1[0] * w2r[g];
                #pragma unroll
                for (int h = 1; h < 8; ++h)
                    z = fmaf(h1[h], w2r[h * 8 + g], z);
                wsum = fmaf(sin_poly(z), w3r[g], wsum);
            }
            kv = wsum * kscale;
        }
        kvr[j] = kv;
    }

    // ---- commit staged window to LDS ----
    #pragma unroll
    for (int i = 0; i < 4; ++i) {
        f_s[(2 * i) * 512 + t]           = q[i].x;
        f_s[(2 * i + 1) * 512 + t]       = q[i].y;
        f_s[(2 * i) * 512 + t + 256]     = q[i + 4].x;
        f_s[(2 * i + 1) * 512 + t + 256] = q[i + 4].y;
    }
    __syncthreads();

    // ---- contraction: acc[b] = sum_j kv[j] * f[b, c, jk0+j] ----
    float acc[NB];
    const float* fp = f_s + joff * 512 + c;
    #pragma unroll
    for (int b = 0; b < NB; ++b) {
        float a = 0.0f;
        #pragma unroll
        for (int j = 0; j < 6; ++j)
            a = fmaf(kvr[j], fp[j * 512 + b * 16], a);
        acc[b] = a;
    }

    // ---- reduce over c (lanes differ in bits 0..3), write partials ----
    #pragma unroll
    for (int b = 0; b < NB; ++b) {
        float v = acc[b];
        v += __shfl_xor(v, 1);
        v += __shfl_xor(v, 2);
        v += __shfl_xor(v, 4);
        v += __shfl_xor(v, 8);
        acc[b] = v;
    }
    if (c == 0) {
        #pragma unroll
        for (int b = 0; b < NB; ++b)
            atomicAdd(&OUT[b * (16 * M_TOT) + o * M_TOT + m], acc[b]);
    }
}

extern "C" void kernel_launch(void* const* d_in, const int* in_sizes, int n_in,
                              void* d_out, int out_size, void* d_ws, size_t ws_size,
                              hipStream_t stream) {
    const float* F  = (const float*)d_in[0];
    const float* OL = (const float*)d_in[1];
    const float* QN = (const float*)d_in[2];
    const float* QW = (const float*)d_in[3];
    const float* W1 = (const float*)d_in[4];
    const float* W2 = (const float*)d_in[5];
    const float* W3 = (const float*)d_in[6];
    float* OUT = (float*)d_out;
    hipMemsetAsync(d_out, 0, (size_t)out_size * sizeof(float), stream);
    quadconv_kernel<<<dim3(SLOTS, M_TOT), dim3(256), 0, stream>>>(F, OL, QN, QW, W1, W2, W3, OUT);
}